// Round 11
// baseline (133.372 us; speedup 1.0000x reference)
//
#include <hip/hip_runtime.h>

// Path signature, depth 4: B=32, L=1024, d=8, fp32.
// Levels: S1(8) S2(64) S3(512) S4(4096); sig stride 4680 floats.
//
// R11 = R7's single-dispatch fused kernel + R10's LDS-staged path (phase A)
// + R9's small-footprint staged folds (phases B/C). 256 blocks x 256 threads
// (co-resident by construction), 2 atomic grid barriers.
//  Phase A: 1024 waves; wave = one 32-inc chunk, FULL sig state in regs
//    (VGPR ~124, proven no-spill in R7); block stages its 129 path rows
//    (4.1 KB) into LDS first - one coalesced latency, then broadcast reads.
//  Phase B: blocks 0..127 fold 8 chunk sigs (levels1-3 double-buffered in
//    2.3KB LDS, B4 k-slice in 16 VGPRs - R9 verbatim).
//  Phase C: blocks 0..31 fold the 4 partials, write d_out.
// Lessons: (R2) never unroll fold loops; (R3) reg headroom or loads
// serialize; (R7/R8) keep prefetch state small or the compiler sinks it /
// collapses VGPRs; (R8) no +4 LDS padding; (R9/R10) floor ~53us is harness
// poison-fill+restore; (R10) residual ~30us ~ 3 dispatch gaps -> fuse to 1.

#define D 8
#define LPATH 1024
#define LASTROW 1023
#define BATCH 32
#define CHUNKS 32
#define MSTEP 32
#define SIG_STRIDE 4680
#define OFF2 8
#define OFF3 72
#define OFF4 584
#define N13F4 146   // 584 floats of levels 1-3 = 146 float4s
#define NBLOCKS 256
#define FLAGS_BYTE_OFF (32u << 20)  // flags 32 MiB into ws (sig data: 19.2 MB)

__device__ __forceinline__ void load8(const float* __restrict__ p, float* dst) {
  float4 lo = *(const float4*)p;
  float4 hi = *(const float4*)(p + 4);
  dst[0] = lo.x; dst[1] = lo.y; dst[2] = lo.z; dst[3] = lo.w;
  dst[4] = hi.x; dst[5] = hi.y; dst[6] = hi.z; dst[7] = hi.w;
}

__device__ __forceinline__ void store8(float* __restrict__ p, const float* src) {
  *(float4*)p       = make_float4(src[0], src[1], src[2], src[3]);
  *(float4*)(p + 4) = make_float4(src[4], src[5], src[6], src[7]);
}

// Grid barrier: 256 blocks co-resident by construction (1 block/CU even at
// max VGPR). Release publishes via L2 writeback; acquire invalidates before
// consuming cross-XCD data. Correctness proven in R7 (absmax matched).
__device__ __forceinline__ void grid_barrier(unsigned int* flag) {
  __syncthreads();
  if (threadIdx.x == 0) {
    __hip_atomic_fetch_add(flag, 1u, __ATOMIC_RELEASE, __HIP_MEMORY_SCOPE_AGENT);
    while (__hip_atomic_load(flag, __ATOMIC_RELAXED, __HIP_MEMORY_SCOPE_AGENT) <
           (unsigned int)NBLOCKS) {
      __builtin_amdgcn_s_sleep(8);
    }
    (void)__hip_atomic_load(flag, __ATOMIC_ACQUIRE, __HIP_MEMORY_SCOPE_AGENT);
  }
  __syncthreads();
}

// ---- fold from LDS levels1-3 + register B4 slice (k-sliced Chen product) ---
__device__ __forceinline__ void fold_lds(const float* __restrict__ L,
                                         const float b4[2][D], float& s1,
                                         float& s2, float s3[D], float s4[2][D],
                                         int i, int j, int lane, int k0) {
  float b1i = L[i];
  float b1j = L[j];
  float sb1[D];
#pragma unroll
  for (int m = 0; m < D; ++m) sb1[m] = L[m];
  float b2own = L[OFF2 + lane];
  float b2row[D], b3own[D];
  *(float4*)&b2row[0] = *(const float4*)&L[OFF2 + j * 8];
  *(float4*)&b2row[4] = *(const float4*)&L[OFF2 + j * 8 + 4];
  *(float4*)&b3own[0] = *(const float4*)&L[OFF3 + lane * 8];
  *(float4*)&b3own[4] = *(const float4*)&L[OFF3 + lane * 8 + 4];

  // C4 = A4 + B4 + A3[i,j,k]B1[m] + A2[i,j]B2[k,m] + A1[i]B3[j,k,m]
#pragma unroll
  for (int t = 0; t < 2; ++t) {
    const int k = k0 + t;
    float b2k[D], b3k[D];
    *(float4*)&b2k[0] = *(const float4*)&L[OFF2 + k * 8];
    *(float4*)&b2k[4] = *(const float4*)&L[OFF2 + k * 8 + 4];
    *(float4*)&b3k[0] = *(const float4*)&L[OFF3 + (j * 8 + k) * 8];
    *(float4*)&b3k[4] = *(const float4*)&L[OFF3 + (j * 8 + k) * 8 + 4];
    float a3k = s3[k];
#pragma unroll
    for (int m = 0; m < D; ++m) {
      float v = __builtin_fmaf(a3k, sb1[m], s4[t][m] + b4[t][m]);
      v = __builtin_fmaf(s2, b2k[m], v);
      s4[t][m] = __builtin_fmaf(s1, b3k[m], v);
    }
  }
  // C3 = A3 + B3 + A1[i]B2[j,k] + A2[i,j]B1[k]
#pragma unroll
  for (int k = 0; k < D; ++k) {
    float v = __builtin_fmaf(s1, b2row[k], s3[k] + b3own[k]);
    s3[k] = __builtin_fmaf(s2, sb1[k], v);
  }
  s2 = s2 + b2own + s1 * b1j;
  s1 = s1 + b1i;
}

// Init state from sig0 at base, fold sigs 1..nsig-1 (stride slots apart).
// lds13: 2 x 584-float tiles. One sync per fold. (R9 verbatim.)
__device__ __forceinline__ void staged_folds(float* __restrict__ base, int stride,
                                             int nsig, float (*lds13)[592],
                                             int tid, int i, int j, int lane,
                                             int k0, float& s1, float& s2,
                                             float s3[D], float s4[2][D]) {
  s1 = base[i];
  s2 = base[OFF2 + lane];
  load8(base + OFF3 + lane * 8, s3);
  load8(base + OFF4 + lane * 64 + k0 * 8, s4[0]);
  load8(base + OFF4 + lane * 64 + (k0 + 1) * 8, s4[1]);

  const float* __restrict__ B1p = base + (size_t)stride * SIG_STRIDE;
  float b4cur[2][D];
  load8(B1p + OFF4 + lane * 64 + k0 * 8, b4cur[0]);
  load8(B1p + OFF4 + lane * 64 + (k0 + 1) * 8, b4cur[1]);
  if (tid < N13F4) {
    float4 sv = *(const float4*)(B1p + tid * 4);
    *(float4*)&lds13[1][tid * 4] = sv;
  }
  __syncthreads();

#pragma unroll 1
  for (int c = 1; c < nsig; ++c) {
    const bool more = (c + 1 < nsig);
    const float* __restrict__ Bn = base + (size_t)(c + 1) * stride * SIG_STRIDE;
    float4 svn;
    float b4n[2][D];
    if (more) {
      if (tid < N13F4) svn = *(const float4*)(Bn + tid * 4);
      load8(Bn + OFF4 + lane * 64 + k0 * 8, b4n[0]);
      load8(Bn + OFF4 + lane * 64 + (k0 + 1) * 8, b4n[1]);
    }

    fold_lds(lds13[c & 1], b4cur, s1, s2, s3, s4, i, j, lane, k0);

    if (more) {
      if (tid < N13F4) *(float4*)&lds13[(c + 1) & 1][tid * 4] = svn;
#pragma unroll
      for (int t = 0; t < 2; ++t)
#pragma unroll
        for (int m = 0; m < D; ++m) b4cur[t][m] = b4n[t][m];
    }
    __syncthreads();
  }
}

__global__ __launch_bounds__(256, 1) void sig_fused(const float* __restrict__ path,
                                                    float* __restrict__ ws,
                                                    float* __restrict__ out,
                                                    unsigned int* __restrict__ flags) {
  __shared__ alignas(16) float lp[129 * D];      // 4.1 KB  (phase A)
  __shared__ alignas(16) float lds13[2][592];    // 4.7 KB  (phases B/C)

  const int tid  = threadIdx.x;
  const int wv   = tid >> 6;               // wave in block 0..3
  const int lane = tid & 63;
  const int i = lane >> 3;
  const int j = lane & 7;

  // ------- Phase A: full-state chunk sig, 1 wave/chunk, path via LDS --------
  {
    const int gw = blockIdx.x * 4 + wv;        // 0..1023 = global chunk id
    const int b  = gw >> 5;
    const int c  = gw & (CHUNKS - 1);
    const int c0 = (blockIdx.x * 4) & (CHUNKS - 1);  // block's first chunk
    const int row0 = c0 * MSTEP;
    const int nrows = (129 < LPATH - row0) ? 129 : (LPATH - row0);
    const int nf4 = nrows * 2;
    const float* __restrict__ bp = path + (size_t)b * (LPATH * D) + (size_t)row0 * D;

#pragma unroll
    for (int it = 0; it < 2; ++it) {
      int n = tid + it * 256;
      if (n < nf4) *(float4*)&lp[4 * n] = *(const float4*)(bp + 4 * n);
    }
    __syncthreads();

    const int rbase = (c - c0) * MSTEP;
    float cm[D];
    *(float4*)&cm[0] = *(const float4*)&lp[rbase * D];
    *(float4*)&cm[4] = *(const float4*)&lp[rbase * D + 4];
    float cwi = lp[rbase * D + i], cwj = lp[rbase * D + j];

    float s1 = 0.f, s2 = 0.f;
    float s3[D] = {0.f, 0.f, 0.f, 0.f, 0.f, 0.f, 0.f, 0.f};
    float s4[D][D];
#pragma unroll
    for (int k = 0; k < D; ++k)
#pragma unroll
      for (int m = 0; m < D; ++m) s4[k][m] = 0.f;

#pragma unroll 1
    for (int t = 0; t < MSTEP; ++t) {
      int grow = c * MSTEP + t + 1;
      grow = grow > LASTROW ? LASTROW : grow;  // clamp -> zero-inc pad
      const int r = grow - row0;
      float nm[D];
      *(float4*)&nm[0] = *(const float4*)&lp[r * D];     // broadcast reads
      *(float4*)&nm[4] = *(const float4*)&lp[r * D + 4];
      float nwi = lp[r * D + i];                         // conflict-free bcast
      float nwj = lp[r * D + j];

      float wm[D];
#pragma unroll
      for (int m = 0; m < D; ++m) wm[m] = nm[m] - cm[m];
      float wi = nwi - cwi, wj = nwj - cwj;

      // level 4: S4 += S3(x)w + S2(x)w^2/2 + S1(x)w^3/6 + w^4/24 (Horner)
      float h1  = __builtin_fmaf(wi, 0.25f, s1);
      float h2  = __builtin_fmaf(h1, wj * (1.f / 3.f), s2);
      float hb2 = h2 * 0.5f;
      float b3[D];
#pragma unroll
      for (int k = 0; k < D; ++k) b3[k] = __builtin_fmaf(hb2, wm[k], s3[k]);
#pragma unroll
      for (int k = 0; k < D; ++k)
#pragma unroll
        for (int m = 0; m < D; ++m)
          s4[k][m] = __builtin_fmaf(b3[k], wm[m], s4[k][m]);

      // level 3
      float c1 = __builtin_fmaf(wi, (1.f / 3.f), s1);
      float c2 = __builtin_fmaf(c1, wj * 0.5f, s2);
#pragma unroll
      for (int k = 0; k < D; ++k) s3[k] = __builtin_fmaf(c2, wm[k], s3[k]);

      // levels 2, 1
      float d1 = __builtin_fmaf(wi, 0.5f, s1);
      s2 = __builtin_fmaf(d1, wj, s2);
      s1 += wi;

#pragma unroll
      for (int m = 0; m < D; ++m) cm[m] = nm[m];
      cwi = nwi; cwj = nwj;
    }

    float* __restrict__ slot = ws + (size_t)(b * CHUNKS + c) * SIG_STRIDE;
    if (j == 0) slot[i] = s1;
    slot[OFF2 + lane] = s2;
    store8(slot + OFF3 + lane * 8, s3);
#pragma unroll
    for (int k = 0; k < D; ++k) store8(slot + OFF4 + lane * 64 + k * 8, s4[k]);
  }

  grid_barrier(&flags[0]);

  // ------- Phase B: blocks 0..127 fold 8 chunk sigs -> partial in slot 8g ---
  if (blockIdx.x < 128) {
    const int bb = blockIdx.x >> 2;
    const int g  = blockIdx.x & 3;
    const int q  = wv;
    const int k0 = q * 2;
    float* __restrict__ base = ws + (size_t)(bb * CHUNKS + g * 8) * SIG_STRIDE;

    float s1, s2, s3[D], s4[2][D];
    staged_folds(base, 1, 8, lds13, tid, i, j, lane, k0, s1, s2, s3, s4);

    store8(base + OFF4 + lane * 64 + k0 * 8, s4[0]);
    store8(base + OFF4 + lane * 64 + (k0 + 1) * 8, s4[1]);
    if (q == 0) {
      if (j == 0) base[i] = s1;
      base[OFF2 + lane] = s2;
      store8(base + OFF3 + lane * 8, s3);
    }
  }

  grid_barrier(&flags[1]);

  // ------- Phase C: blocks 0..31 fold the 4 partials -> d_out ---------------
  if (blockIdx.x < 32) {
    const int bb = blockIdx.x;
    const int q  = wv;
    const int k0 = q * 2;
    float* __restrict__ base = ws + (size_t)bb * CHUNKS * SIG_STRIDE;

    float s1, s2, s3[D], s4[2][D];
    staged_folds(base, 8, 4, lds13, tid, i, j, lane, k0, s1, s2, s3, s4);

    // d_out: S1 (32x8) | S2 (32x64) | S3 (32x512) | S4 (32x4096)
    if (q == 0) {
      if (j == 0) out[bb * 8 + i] = s1;
      out[256 + bb * 64 + lane] = s2;
      store8(out + 2304 + bb * 512 + lane * 8, s3);
    }
    store8(out + 18688 + bb * 4096 + lane * 64 + k0 * 8, s4[0]);
    store8(out + 18688 + bb * 4096 + lane * 64 + (k0 + 1) * 8, s4[1]);
  }
}

extern "C" void kernel_launch(void* const* d_in, const int* in_sizes, int n_in,
                              void* d_out, int out_size, void* d_ws, size_t ws_size,
                              hipStream_t stream) {
  const float* path = (const float*)d_in[0];
  // d_in[1] = depth (==4), compile-time specialized.
  float* out = (float*)d_out;
  float* ws  = (float*)d_ws;  // sig data: first 19.2 MB; flags at +32 MiB
  unsigned int* flags = (unsigned int*)((char*)d_ws + FLAGS_BYTE_OFF);

  hipMemsetAsync(flags, 0, 2 * sizeof(unsigned int), stream);
  sig_fused<<<dim3(NBLOCKS), dim3(256), 0, stream>>>(path, ws, out, flags);
}